// Round 2
// baseline (108.588 us; speedup 1.0000x reference)
//
#include <hip/hip_runtime.h>
#include <hip/hip_bf16.h>

// Problem: B=2, DIM=512, NUM_HEADS=1, tokens TOK=256 (16x16 window, w=1).
// Pipeline: [gemm qkv (Ksplit2)] -> [fused per-channel attention] ->
//           [gemm proj (Ksplit4)] -> [combine + proj bias]
// All fp32. Workspace layout (floats):
//   qkvp  = ws + 0        : 2 parts * [2][1536][256] = 1,572,864
//   aout  = ws + 1572864  : [2][512][256]            =   262,144
//   projp = ws + 1835008  : 4 parts * [2][512][256]  = 1,048,576
// total 2,883,584 floats = 11,534,336 bytes of d_ws.

#define TOK   256
#define KDIM  512
#define LOG2E 1.4426950408889634f
#define SCALE 0.04419417382415922f   // 512^{-1/2}

// v_exp_f32 (base-2) — __exp2f collides with glibc math.h, use the builtin.
#define EXP2(x) __builtin_amdgcn_exp2f(x)

// ---------------------------------------------------------------------------
// fp32 GEMM with K-split:  Cpart[ks][b][M][TOK] = A[M x 512] @ B[b][512][TOK]
// 64x64 tile, BK=16, 256 threads, 4x4 microtile per thread.
// ---------------------------------------------------------------------------
template<int KSPLIT>
__global__ __launch_bounds__(256)
void gemm_f32(const float* __restrict__ A, const float* __restrict__ B,
              float* __restrict__ C, int M)
{
    constexpr int KLEN = KDIM / KSPLIT;
    const int t  = threadIdx.x;
    const int ty = t >> 4;                 // 0..15 -> o rows (x4)
    const int tx = t & 15;                 // 0..15 -> h cols (x4)
    const int o0 = blockIdx.x * 64;
    const int h0 = blockIdx.y * 64;
    const int b  = blockIdx.z / KSPLIT;
    const int ks = blockIdx.z % KSPLIT;

    const float* Ab = A + (size_t)o0 * KDIM + ks * KLEN;
    const float* Bb = B + ((size_t)b * KDIM + (size_t)ks * KLEN) * TOK + h0;
    float*       Cb = C + (((size_t)(ks * 2 + b) * M) + o0) * TOK + h0;

    __shared__ float As[16][64];   // [k][o] (transposed store -> b128 frag reads)
    __shared__ float Bs[16][64];   // [k][h]

    const int ar  = t >> 2;        // 0..63  A row
    const int ac4 = (t & 3) * 4;   // A col quad
    const int bk  = t >> 4;        // 0..15  B k-row
    const int bh4 = (t & 15) * 4;  // B col quad

    float acc[4][4];
#pragma unroll
    for (int i = 0; i < 4; ++i)
#pragma unroll
        for (int j = 0; j < 4; ++j) acc[i][j] = 0.f;

    for (int k0 = 0; k0 < KLEN; k0 += 16) {
        const float4 av = *(const float4*)(Ab + (size_t)ar * KDIM + (k0 + ac4));
        const float4 bv = *(const float4*)(Bb + (size_t)(k0 + bk) * TOK + bh4);
        __syncthreads();
        As[ac4 + 0][ar] = av.x;
        As[ac4 + 1][ar] = av.y;
        As[ac4 + 2][ar] = av.z;
        As[ac4 + 3][ar] = av.w;
        *(float4*)&Bs[bk][bh4] = bv;
        __syncthreads();
#pragma unroll
        for (int kk = 0; kk < 16; ++kk) {
            const float4 a4 = *(const float4*)&As[kk][ty * 4];
            const float4 b4 = *(const float4*)&Bs[kk][tx * 4];
            const float a[4] = {a4.x, a4.y, a4.z, a4.w};
            const float bb[4] = {b4.x, b4.y, b4.z, b4.w};
#pragma unroll
            for (int i = 0; i < 4; ++i)
#pragma unroll
                for (int j = 0; j < 4; ++j)
                    acc[i][j] = fmaf(a[i], bb[j], acc[i][j]);
        }
    }

#pragma unroll
    for (int i = 0; i < 4; ++i) {
        const float4 o4 = make_float4(acc[i][0], acc[i][1], acc[i][2], acc[i][3]);
        *(float4*)(Cb + (size_t)(ty * 4 + i) * TOK + tx * 4) = o4;
    }
}

// ---------------------------------------------------------------------------
// Fused per-channel attention.
// Block = 256 threads handles (b, d0..d0+1): waves = (dl, g-half).
// Each thread owns 4 consecutive h (h = 4*qi..4*qi+3), loops over its g-half.
// bias[h,g] = tab[r(h)-r(g)+30], r(h)=(h>>4)+(h&15): 61 distinct values,
// replicated into brow[31][258] so inner reads are aligned float2, 2-bank
// stride (conflict-free). No softmax max-subtraction (scores bounded ~1.1),
// so g-half partials (l, acc) merge additively.
// ---------------------------------------------------------------------------
__global__ __launch_bounds__(256)
void attn_f32(const float* __restrict__ qkvp, const float* __restrict__ qkv_b,
              const float* __restrict__ rpb, float* __restrict__ aout)
{
    __shared__ float ks_[2][TOK];      // k * scale * log2e (incl. qkv bias)
    __shared__ float vs_[2][TOK];      // v (incl. qkv bias)
    __shared__ float tab2[64];         // rpb gathered, * log2e
    __shared__ float brow[31][258];    // bias rows, stride 258 (2-bank step)
    __shared__ float lpart[2][TOK];
    __shared__ float apart[2][TOK];

    const int t  = threadIdx.x;
    const int b  = blockIdx.y;
    const int d0 = blockIdx.x * 2;
    const float* q0 = qkvp + (size_t)b * (1536 * TOK);
    const size_t P1 = (size_t)786432;  // stride between the 2 K-split parts

    // phase 0: bias table (61 values)
    if (t < 61) {
        const int rel = t - 30;
        tab2[t] = rpb[rel < 0 ? rel + 961 : rel] * LOG2E;
    }
    // phase 1: stage k2 and v for the 2 channels (sum K-split parts + bias)
    {
        const int sel = t >> 7;          // 0: k, 1: v
        const int row = (t >> 6) & 1;    // dl
        const int g4  = (t & 63) * 4;
        const int o   = (sel ? 1024 : 512) + d0 + row;
        const float* p = q0 + (size_t)o * TOK + g4;
        const float4 x0 = *(const float4*)p;
        const float4 x1 = *(const float4*)(p + P1);
        const float bb = qkv_b[o];
        float4 v;
        v.x = x0.x + x1.x + bb;
        v.y = x0.y + x1.y + bb;
        v.z = x0.z + x1.z + bb;
        v.w = x0.w + x1.w + bb;
        if (sel == 0) {
            const float s = SCALE * LOG2E;
            v.x *= s; v.y *= s; v.z *= s; v.w *= s;
            *(float4*)&ks_[row][g4] = v;
        } else {
            *(float4*)&vs_[row][g4] = v;
        }
    }
    __syncthreads();
    // phase 2: replicate bias into 31 rows x 256 g
    {
        const int rg = ((t >> 4) & 15) + (t & 15);
#pragma unroll 1
        for (int it = 0; it < 31; ++it)
            brow[it][t] = tab2[it - rg + 30];
    }
    __syncthreads();

    // phase 3: main loop
    const int w   = t >> 6;
    const int dl  = w & 1;
    const int gh  = w >> 1;
    const int hl  = t & 63;
    const int qi  = ((hl & 15) << 2) | (hl >> 4);  // bit-swizzled h-quad index
    const int h0  = qi * 4;
    const int rh0 = (qi >> 2) + 4 * (qi & 3);      // r(h0); r(h0+r)=rh0+r

    float q[4];
    {
        const float* p = q0 + (size_t)(d0 + dl) * TOK + h0;
        const float4 x0 = *(const float4*)p;
        const float4 x1 = *(const float4*)(p + P1);
        const float bb = qkv_b[d0 + dl];
        q[0] = x0.x + x1.x + bb;
        q[1] = x0.y + x1.y + bb;
        q[2] = x0.z + x1.z + bb;
        q[3] = x0.w + x1.w + bb;
    }

    float l[4]  = {0.f, 0.f, 0.f, 0.f};
    float am[4] = {0.f, 0.f, 0.f, 0.f};

    const int pbeg = gh * 128;
#pragma unroll 2
    for (int p = pbeg; p < pbeg + 128; p += 4) {
        const float4 k4 = *(const float4*)&ks_[dl][p];   // wave-uniform (bcast)
        const float4 v4 = *(const float4*)&vs_[dl][p];
#pragma unroll
        for (int r = 0; r < 4; ++r) {
            const float2 b01 = *(const float2*)&brow[rh0 + r][p];
            const float2 b23 = *(const float2*)&brow[rh0 + r][p + 2];
            float e;
            e = EXP2(fmaf(q[r], k4.x, b01.x)); l[r] += e; am[r] = fmaf(e, v4.x, am[r]);
            e = EXP2(fmaf(q[r], k4.y, b01.y)); l[r] += e; am[r] = fmaf(e, v4.y, am[r]);
            e = EXP2(fmaf(q[r], k4.z, b23.x)); l[r] += e; am[r] = fmaf(e, v4.z, am[r]);
            e = EXP2(fmaf(q[r], k4.w, b23.y)); l[r] += e; am[r] = fmaf(e, v4.w, am[r]);
        }
    }

    // phase 4: merge g-halves, normalize, store
    if (gh == 1) {
        *(float4*)&lpart[dl][h0] = make_float4(l[0], l[1], l[2], l[3]);
        *(float4*)&apart[dl][h0] = make_float4(am[0], am[1], am[2], am[3]);
    }
    __syncthreads();
    if (gh == 0) {
        const float4 lo = *(const float4*)&lpart[dl][h0];
        const float4 ao = *(const float4*)&apart[dl][h0];
        float4 o4;
        o4.x = (am[0] + ao.x) / (l[0] + lo.x);
        o4.y = (am[1] + ao.y) / (l[1] + lo.y);
        o4.z = (am[2] + ao.z) / (l[2] + lo.z);
        o4.w = (am[3] + ao.w) / (l[3] + lo.w);
        *(float4*)(aout + ((size_t)b * 512 + d0 + dl) * TOK + h0) = o4;
    }
}

// ---------------------------------------------------------------------------
// Sum the 4 proj K-split parts + proj bias -> final output [2][512][256]
// ---------------------------------------------------------------------------
__global__ __launch_bounds__(256)
void combine_f32(const float* __restrict__ pp, const float* __restrict__ pb,
                 float* __restrict__ out)
{
    const int gid  = blockIdx.x * 256 + threadIdx.x;
    const int flat = gid * 4;
    const int o = (flat >> 8) & 511;
    float4 a        = *(const float4*)(pp + flat);
    const float4 b4 = *(const float4*)(pp + 262144 + flat);
    const float4 c4 = *(const float4*)(pp + 524288 + flat);
    const float4 d4 = *(const float4*)(pp + 786432 + flat);
    const float bias = pb[o];
    a.x += b4.x + c4.x + d4.x + bias;
    a.y += b4.y + c4.y + d4.y + bias;
    a.z += b4.z + c4.z + d4.z + bias;
    a.w += b4.w + c4.w + d4.w + bias;
    *(float4*)(out + flat) = a;
}

// ---------------------------------------------------------------------------
extern "C" void kernel_launch(void* const* d_in, const int* in_sizes, int n_in,
                              void* d_out, int out_size, void* d_ws, size_t ws_size,
                              hipStream_t stream)
{
    const float* x      = (const float*)d_in[0];   // [2][512][256]
    const float* qkv_w  = (const float*)d_in[1];   // [1536][512]
    const float* qkv_b  = (const float*)d_in[2];   // [1536]
    const float* proj_w = (const float*)d_in[3];   // [512][512]
    const float* proj_b = (const float*)d_in[4];   // [512]
    const float* rpb    = (const float*)d_in[5];   // [961]
    float* out = (float*)d_out;                    // [2][512][256]
    float* ws  = (float*)d_ws;

    float* qkvp  = ws;                 // 2 * 786432
    float* aout  = ws + 1572864;       // 262144
    float* projp = ws + 1835008;       // 4 * 262144

    // qkv = qkv_w @ x  (M=1536, Ksplit=2): grid (1536/64, 256/64, 2b*2ks)
    gemm_f32<2><<<dim3(24, 4, 4), 256, 0, stream>>>(qkv_w, x, qkvp, 1536);

    // fused attention: grid (d-pairs=256, b=2)
    attn_f32<<<dim3(256, 2), 256, 0, stream>>>(qkvp, qkv_b, rpb, aout);

    // proj = proj_w @ aout (M=512, Ksplit=4): grid (512/64, 256/64, 2b*4ks)
    gemm_f32<4><<<dim3(8, 4, 8), 256, 0, stream>>>(proj_w, aout, projp, 512);

    // sum 4 parts + bias
    combine_f32<<<dim3(256), 256, 0, stream>>>(projp, proj_b, out);
}

// Round 3
// 103.336 us; speedup vs baseline: 1.0508x; 1.0508x over previous
//
#include <hip/hip_runtime.h>
#include <hip/hip_bf16.h>

// Problem: B=2, DIM=512, NUM_HEADS=1, tokens TOK=256 (16x16 window, w=1).
// Pipeline: [gemm qkv (Ksplit8)] -> [fused per-channel attention, sums 8 parts]
//           -> [gemm proj (Ksplit8)] -> [combine 8 parts + proj bias]
// All fp32. Workspace layout (floats):
//   qkvp  = ws + 0        : 16 parts(ks*2+b) * [1536][256] = 6,291,456
//   aout  = ws + 6291456  : [2][512][256]                  =   262,144
//   projp = ws + 6553600  : 16 parts(ks*2+b) * [512][256]  = 2,097,152
// total 8,650,752 floats = 34.6 MB of d_ws.

#define TOK   256
#define KDIM  512
#define LOG2E 1.4426950408889634f
#define SCALE 0.04419417382415922f   // 512^{-1/2}
#define NPART 8
#define QPSTRIDE 786432              // 2*1536*256, qkv ks-part stride (fixed b)
#define PPSTRIDE 262144              // 2*512*256,  proj ks-part stride

// v_exp_f32 (base-2) — __exp2f collides with glibc math.h, use the builtin.
#define EXP2(x) __builtin_amdgcn_exp2f(x)

// ---------------------------------------------------------------------------
// fp32 GEMM, K-split, double-buffered LDS (1 barrier/iter), reg prefetch d=1.
// Cpart[z=(ks*2+b)][M][TOK] = A[M x KLEN slice] @ B[b][KLEN slice][TOK]
// BM x 64 tile, BK=16, 256 threads, (BM/16) x 4 microtile per thread.
// qkv: BM=128, KSPLIT=8 -> 768 blocks (3/CU). proj: BM=64 -> 512 blocks (2/CU).
// ---------------------------------------------------------------------------
template<int BM, int KSPLIT>
__global__ __launch_bounds__(256)
void gemm_f32(const float* __restrict__ A, const float* __restrict__ B,
              float* __restrict__ C, int M)
{
    constexpr int KLEN  = KDIM / KSPLIT;
    constexpr int NITER = KLEN / 16;
    constexpr int MM    = BM / 16;        // micro rows per thread (8 or 4)
    constexpr int LDA   = BM + 4;         // pad: transpose-store 2-way max

    __shared__ float As[2][16][LDA];      // [buf][k][m]
    __shared__ float Bs[2][16][64];       // [buf][k][n]

    const int t  = threadIdx.x;
    const int o0 = blockIdx.x * BM;
    const int n0 = blockIdx.y * 64;
    const int b  = blockIdx.z & 1;
    const int ks = blockIdx.z >> 1;

    const float* Ab = A + (size_t)o0 * KDIM + ks * KLEN;
    const float* Bb = B + ((size_t)b * KDIM + (size_t)ks * KLEN) * TOK + n0;
    float*       Cb = C + ((size_t)blockIdx.z * M + o0) * TOK + n0;

    // staging maps
    const int ar  = t >> 2;               // A row 0..63 (and +64 if BM=128)
    const int ac4 = (t & 3) * 4;          // A k-quad
    const int bk  = t >> 4;               // B k-row 0..15
    const int bn4 = (t & 15) * 4;         // B n-quad

    float4 ra0, ra1, rb;
#define LOAD_TILE(IT) do {                                                   \
        const int k0_ = (IT) * 16;                                           \
        ra0 = *(const float4*)(Ab + (size_t)ar * KDIM + k0_ + ac4);          \
        if (BM == 128)                                                       \
            ra1 = *(const float4*)(Ab + (size_t)(64 + ar) * KDIM + k0_ + ac4);\
        rb  = *(const float4*)(Bb + (size_t)(k0_ + bk) * TOK + bn4);         \
    } while (0)
#define STORE_TILE(BUF) do {                                                 \
        As[BUF][ac4 + 0][ar] = ra0.x;                                        \
        As[BUF][ac4 + 1][ar] = ra0.y;                                        \
        As[BUF][ac4 + 2][ar] = ra0.z;                                        \
        As[BUF][ac4 + 3][ar] = ra0.w;                                        \
        if (BM == 128) {                                                     \
            As[BUF][ac4 + 0][64 + ar] = ra1.x;                               \
            As[BUF][ac4 + 1][64 + ar] = ra1.y;                               \
            As[BUF][ac4 + 2][64 + ar] = ra1.z;                               \
            As[BUF][ac4 + 3][64 + ar] = ra1.w;                               \
        }                                                                    \
        *(float4*)&Bs[BUF][bk][bn4] = rb;                                    \
    } while (0)

    const int m0 = (t >> 4) * MM;
    const int n4 = (t & 15) * 4;

    float acc[MM][4];
#pragma unroll
    for (int i = 0; i < MM; ++i)
#pragma unroll
        for (int j = 0; j < 4; ++j) acc[i][j] = 0.f;

    LOAD_TILE(0);
    STORE_TILE(0);
    if (NITER > 1) LOAD_TILE(1);
    __syncthreads();

#pragma unroll
    for (int it = 0; it < NITER; ++it) {
        const int cur = it & 1;
        if (it + 1 < NITER) STORE_TILE(1 - cur);   // store prefetched tile it+1
        if (it + 2 < NITER) LOAD_TILE(it + 2);     // issue load, lands next iter
#pragma unroll
        for (int kk = 0; kk < 16; ++kk) {
            const float4 b4 = *(const float4*)&Bs[cur][kk][n4];
            float af[MM];
#pragma unroll
            for (int mi = 0; mi < MM; mi += 4) {
                const float4 a4 = *(const float4*)&As[cur][kk][m0 + mi];
                af[mi + 0] = a4.x; af[mi + 1] = a4.y;
                af[mi + 2] = a4.z; af[mi + 3] = a4.w;
            }
#pragma unroll
            for (int mi = 0; mi < MM; ++mi) {
                acc[mi][0] = fmaf(af[mi], b4.x, acc[mi][0]);
                acc[mi][1] = fmaf(af[mi], b4.y, acc[mi][1]);
                acc[mi][2] = fmaf(af[mi], b4.z, acc[mi][2]);
                acc[mi][3] = fmaf(af[mi], b4.w, acc[mi][3]);
            }
        }
        __syncthreads();
    }

#pragma unroll
    for (int mi = 0; mi < MM; ++mi) {
        const float4 o4 = make_float4(acc[mi][0], acc[mi][1], acc[mi][2], acc[mi][3]);
        *(float4*)(Cb + (size_t)(m0 + mi) * TOK + n4) = o4;
    }
#undef LOAD_TILE
#undef STORE_TILE
}

// ---------------------------------------------------------------------------
// Fused per-channel attention (sums the 8 qkv K-split parts inline).
// Block = 256 threads handles (b, d0..d0+1): waves = (dl, g-half).
// bias[h,g] = tab[r(h)-r(g)+30], r(h)=(h>>4)+(h&15): 61 distinct values,
// replicated into brow[31][258] (2-bank step, conflict-free float2 reads).
// Scores bounded (~1.1) -> no max-subtraction; g-half partials merge additively.
// ---------------------------------------------------------------------------
__global__ __launch_bounds__(256)
void attn_f32(const float* __restrict__ qkvp, const float* __restrict__ qkv_b,
              const float* __restrict__ rpb, float* __restrict__ aout)
{
    __shared__ float ks_[2][TOK];      // k * scale * log2e (incl. qkv bias)
    __shared__ float vs_[2][TOK];      // v (incl. qkv bias)
    __shared__ float tab2[64];         // rpb gathered, * log2e
    __shared__ float brow[31][258];    // bias rows, stride 258 (2-bank step)
    __shared__ float lpart[2][TOK];
    __shared__ float apart[2][TOK];

    const int t  = threadIdx.x;
    const int b  = blockIdx.y;
    const int d0 = blockIdx.x * 2;
    const float* q0 = qkvp + (size_t)b * (1536 * TOK);

    // phase 0: bias table (61 values)
    if (t < 61) {
        const int rel = t - 30;
        tab2[t] = rpb[rel < 0 ? rel + 961 : rel] * LOG2E;
    }
    // phase 1: stage k and v for the 2 channels (sum 8 K-split parts + bias)
    {
        const int sel = t >> 7;          // 0: k, 1: v
        const int row = (t >> 6) & 1;    // dl
        const int g4  = (t & 63) * 4;
        const int o   = (sel ? 1024 : 512) + d0 + row;
        const float* p = q0 + (size_t)o * TOK + g4;
        const float bb = qkv_b[o];
        float4 v = make_float4(bb, bb, bb, bb);
#pragma unroll
        for (int pp = 0; pp < NPART; ++pp) {
            const float4 x = *(const float4*)(p + (size_t)pp * QPSTRIDE);
            v.x += x.x; v.y += x.y; v.z += x.z; v.w += x.w;
        }
        if (sel == 0) {
            const float s = SCALE * LOG2E;
            v.x *= s; v.y *= s; v.z *= s; v.w *= s;
            *(float4*)&ks_[row][g4] = v;
        } else {
            *(float4*)&vs_[row][g4] = v;
        }
    }
    __syncthreads();
    // phase 2: replicate bias into 31 rows x 256 g
    {
        const int rg = ((t >> 4) & 15) + (t & 15);
#pragma unroll 1
        for (int it = 0; it < 31; ++it)
            brow[it][t] = tab2[it - rg + 30];
    }
    __syncthreads();

    // phase 3: main loop
    const int w   = t >> 6;
    const int dl  = w & 1;
    const int gh  = w >> 1;
    const int hl  = t & 63;
    const int qi  = ((hl & 15) << 2) | (hl >> 4);  // bit-swizzled h-quad index
    const int h0  = qi * 4;
    const int rh0 = (qi >> 2) + 4 * (qi & 3);      // r(h0); r(h0+r)=rh0+r

    float q[4];
    {
        const float* p = q0 + (size_t)(d0 + dl) * TOK + h0;
        const float bb = qkv_b[d0 + dl];
        q[0] = bb; q[1] = bb; q[2] = bb; q[3] = bb;
#pragma unroll
        for (int pp = 0; pp < NPART; ++pp) {
            const float4 x = *(const float4*)(p + (size_t)pp * QPSTRIDE);
            q[0] += x.x; q[1] += x.y; q[2] += x.z; q[3] += x.w;
        }
    }

    float l[4]  = {0.f, 0.f, 0.f, 0.f};
    float am[4] = {0.f, 0.f, 0.f, 0.f};

    const int pbeg = gh * 128;
#pragma unroll 2
    for (int p = pbeg; p < pbeg + 128; p += 4) {
        const float4 k4 = *(const float4*)&ks_[dl][p];   // wave-uniform (bcast)
        const float4 v4 = *(const float4*)&vs_[dl][p];
#pragma unroll
        for (int r = 0; r < 4; ++r) {
            const float2 b01 = *(const float2*)&brow[rh0 + r][p];
            const float2 b23 = *(const float2*)&brow[rh0 + r][p + 2];
            float e;
            e = EXP2(fmaf(q[r], k4.x, b01.x)); l[r] += e; am[r] = fmaf(e, v4.x, am[r]);
            e = EXP2(fmaf(q[r], k4.y, b01.y)); l[r] += e; am[r] = fmaf(e, v4.y, am[r]);
            e = EXP2(fmaf(q[r], k4.z, b23.x)); l[r] += e; am[r] = fmaf(e, v4.z, am[r]);
            e = EXP2(fmaf(q[r], k4.w, b23.y)); l[r] += e; am[r] = fmaf(e, v4.w, am[r]);
        }
    }

    // phase 4: merge g-halves, normalize, store
    if (gh == 1) {
        *(float4*)&lpart[dl][h0] = make_float4(l[0], l[1], l[2], l[3]);
        *(float4*)&apart[dl][h0] = make_float4(am[0], am[1], am[2], am[3]);
    }
    __syncthreads();
    if (gh == 0) {
        const float4 lo = *(const float4*)&lpart[dl][h0];
        const float4 ao = *(const float4*)&apart[dl][h0];
        float4 o4;
        o4.x = (am[0] + ao.x) / (l[0] + lo.x);
        o4.y = (am[1] + ao.y) / (l[1] + lo.y);
        o4.z = (am[2] + ao.z) / (l[2] + lo.z);
        o4.w = (am[3] + ao.w) / (l[3] + lo.w);
        *(float4*)(aout + ((size_t)b * 512 + d0 + dl) * TOK + h0) = o4;
    }
}

// ---------------------------------------------------------------------------
// Sum the 8 proj K-split parts + proj bias -> final output [2][512][256]
// ---------------------------------------------------------------------------
__global__ __launch_bounds__(256)
void combine_f32(const float* __restrict__ pp, const float* __restrict__ pb,
                 float* __restrict__ out)
{
    const int gid  = blockIdx.x * 256 + threadIdx.x;
    const int flat = gid * 4;
    const int o = (flat >> 8) & 511;
    float4 a = make_float4(pb[o], pb[o], pb[o], pb[o]);
#pragma unroll
    for (int p = 0; p < NPART; ++p) {
        const float4 x = *(const float4*)(pp + (size_t)p * PPSTRIDE + flat);
        a.x += x.x; a.y += x.y; a.z += x.z; a.w += x.w;
    }
    *(float4*)(out + flat) = a;
}

// ---------------------------------------------------------------------------
extern "C" void kernel_launch(void* const* d_in, const int* in_sizes, int n_in,
                              void* d_out, int out_size, void* d_ws, size_t ws_size,
                              hipStream_t stream)
{
    const float* x      = (const float*)d_in[0];   // [2][512][256]
    const float* qkv_w  = (const float*)d_in[1];   // [1536][512]
    const float* qkv_b  = (const float*)d_in[2];   // [1536]
    const float* proj_w = (const float*)d_in[3];   // [512][512]
    const float* proj_b = (const float*)d_in[4];   // [512]
    const float* rpb    = (const float*)d_in[5];   // [961]
    float* out = (float*)d_out;                    // [2][512][256]
    float* ws  = (float*)d_ws;

    float* qkvp  = ws;                 // 16 * 393216
    float* aout  = ws + 6291456;       // 262144
    float* projp = ws + 6553600;       // 16 * 131072

    // qkv = qkv_w @ x: M=1536, BM=128, Ksplit=8 -> grid (12, 4, 16) = 768 blocks
    gemm_f32<128, 8><<<dim3(12, 4, 16), 256, 0, stream>>>(qkv_w, x, qkvp, 1536);

    // fused attention: grid (d-pairs=256, b=2)
    attn_f32<<<dim3(256, 2), 256, 0, stream>>>(qkvp, qkv_b, rpb, aout);

    // proj = proj_w @ aout: M=512, BM=64, Ksplit=8 -> grid (8, 4, 16) = 512 blocks
    gemm_f32<64, 8><<<dim3(8, 4, 16), 256, 0, stream>>>(proj_w, aout, projp, 512);

    // sum 8 parts + bias
    combine_f32<<<dim3(256), 256, 0, stream>>>(projp, proj_b, out);
}